// Round 3
// baseline (940.631 us; speedup 1.0000x reference)
//
#include <hip/hip_runtime.h>

namespace {
constexpr int NB = 16, NH = 256, NW = 256, NC = 64;
constexpr int NM1 = 20, NM2 = 20;
constexpr int MC = NM2 * NC;        // 1280
constexpr int RC = NW * NC;         // 16384 floats per (b,h) row
constexpr float STEP = 6.283185307179586f / 256.0f;

// ws layout (float offsets). g_re/g_im alias tmpW (dead after k_fwd_h).
constexpr size_t OFF_E1   = 0;                               // float2[20*256]
constexpr size_t OFF_E2   = OFF_E1 + 2ull * NM1 * NH;        // float2[20*256]
constexpr size_t OFF_IKC  = OFF_E2 + 2ull * NM2 * NW;        // float[20*256]
constexpr size_t OFF_IKS  = OFF_IKC + (size_t)NM2 * NW;
constexpr size_t OFF_TWRE = OFF_IKS + (size_t)NM2 * NW;
constexpr size_t NTW      = (size_t)NB * NH * MC;            // 5,242,880
constexpr size_t OFF_TWIM = OFF_TWRE + NTW;
constexpr size_t OFF_PRE  = OFF_TWIM + NTW;
constexpr size_t NPART    = (size_t)NB * 8 * NM1 * MC;       // 3,276,800
constexpr size_t OFF_PIM  = OFF_PRE + NPART;
constexpr size_t OFF_MORE = OFF_PIM + NPART;
constexpr size_t NMO      = (size_t)NB * NM1 * MC;           // 409,600
constexpr size_t OFF_MOIM = OFF_MORE + NMO;
}

__device__ __forceinline__ unsigned short f2bf(float f) {
  unsigned int u = __float_as_uint(f);
  unsigned int r = u + 0x7FFFu + ((u >> 16) & 1u);
  return (unsigned short)(r >> 16);
}
__device__ __forceinline__ void unpack8(uint4 u, float* v) {
  v[0] = __uint_as_float(u.x << 16); v[1] = __uint_as_float(u.x & 0xFFFF0000u);
  v[2] = __uint_as_float(u.y << 16); v[3] = __uint_as_float(u.y & 0xFFFF0000u);
  v[4] = __uint_as_float(u.z << 16); v[5] = __uint_as_float(u.z & 0xFFFF0000u);
  v[6] = __uint_as_float(u.w << 16); v[7] = __uint_as_float(u.w & 0xFFFF0000u);
}

// ---- trig tables --------------------------------------------------------
__global__ __launch_bounds__(256) void k_tables(float* __restrict__ ws) {
  int idx = blockIdx.x * 256 + threadIdx.x;
  if (idx >= NM1 * NH) return;
  int m = idx >> 8, x = idx & 255;
  // e1: frequency kx = m-10 (idx1 wraps to exactly this), theta = 2*pi*kx*x/256
  int kx = m - 10;
  int ph1 = ((kx * x) % 256 + 256) & 255;
  float s1, c1; sincosf(ph1 * STEP, &s1, &c1);
  ((float2*)(ws + OFF_E1))[idx] = make_float2(c1, s1);
  // e2: ky = m
  int ph2 = (m * x) & 255;
  float s2, c2; sincosf(ph2 * STEP, &s2, &c2);
  ((float2*)(ws + OFF_E2))[idx] = make_float2(c2, s2);
  // inverse-W synthesis: (1/HW)*scale*(cos, -sin); ky=0 -> iks=0 drops Im(DC)
  float sc = (m == 0 ? 1.0f : 2.0f) / 65536.0f;
  ws[OFF_IKC + idx] = sc * c2;
  ws[OFF_IKS + idx] = -sc * s2;
}

// ---- forward W-DFT: one wave per (b,h) row ------------------------------
__global__ __launch_bounds__(256) void k_fwd_w(const float* __restrict__ pts,
                                               float* __restrict__ ws) {
  const int lane = threadIdx.x & 63;
  const int wave = threadIdx.x >> 6;
  const int r = blockIdx.x * 4 + wave;           // b*256+h
  const int tc = lane & 15;                      // c0 = 4*tc
  const int grp = lane >> 4;                     // m2 = grp*5+k
  const float4* __restrict__ prow = (const float4*)(pts + (size_t)r * RC);
  const float2* __restrict__ e2 = (const float2*)(ws + OFF_E2);
  float ar[5][4], ai[5][4];
#pragma unroll
  for (int k = 0; k < 5; ++k)
#pragma unroll
    for (int q = 0; q < 4; ++q) { ar[k][q] = 0.f; ai[k][q] = 0.f; }
  for (int w = 0; w < NW; ++w) {
    float4 p = prow[w * 16 + tc];
#pragma unroll
    for (int k = 0; k < 5; ++k) {
      float2 cs = e2[(grp * 5 + k) * 256 + w];   // e^{-i t} = c - i s
      ar[k][0] += p.x * cs.x; ar[k][1] += p.y * cs.x;
      ar[k][2] += p.z * cs.x; ar[k][3] += p.w * cs.x;
      ai[k][0] -= p.x * cs.y; ai[k][1] -= p.y * cs.y;
      ai[k][2] -= p.z * cs.y; ai[k][3] -= p.w * cs.y;
    }
  }
  float* tre = ws + OFF_TWRE + (size_t)r * MC;
  float* tim = ws + OFF_TWIM + (size_t)r * MC;
#pragma unroll
  for (int k = 0; k < 5; ++k) {
    int o = (grp * 5 + k) * 64 + tc * 4;
    *(float4*)(tre + o) = make_float4(ar[k][0], ar[k][1], ar[k][2], ar[k][3]);
    *(float4*)(tim + o) = make_float4(ai[k][0], ai[k][1], ai[k][2], ai[k][3]);
  }
}

// ---- forward H-DFT: partial sums over 32-h chunks -----------------------
__global__ __launch_bounds__(256) void k_fwd_h(float* __restrict__ ws) {
  const int bid = blockIdx.x;                    // b*16 + chunk*2 + half
  const int half = bid & 1;
  const int chunk = (bid >> 1) & 7;
  const int b = bid >> 4;
  const int tid = threadIdx.x;
  const float2* __restrict__ e1 = (const float2*)(ws + OFF_E1);
  const float* __restrict__ tre = ws + OFF_TWRE;
  const float* __restrict__ tim = ws + OFF_TWIM;
  float ar[10][5], ai[10][5];
#pragma unroll
  for (int mm = 0; mm < 10; ++mm)
#pragma unroll
    for (int k = 0; k < 5; ++k) { ar[mm][k] = 0.f; ai[mm][k] = 0.f; }
  for (int hh = 0; hh < 32; ++hh) {
    int h = chunk * 32 + hh;
    size_t base = (size_t)(b * 256 + h) * MC + tid;
    float tr[5], ti[5];
#pragma unroll
    for (int k = 0; k < 5; ++k) { tr[k] = tre[base + 256 * k]; ti[k] = tim[base + 256 * k]; }
#pragma unroll
    for (int mm = 0; mm < 10; ++mm) {
      float2 cs = e1[(half * 10 + mm) * 256 + h];   // multiply by (c - i s)
#pragma unroll
      for (int k = 0; k < 5; ++k) {
        ar[mm][k] += tr[k] * cs.x + ti[k] * cs.y;
        ai[mm][k] += ti[k] * cs.x - tr[k] * cs.y;
      }
    }
  }
  for (int mm = 0; mm < 10; ++mm) {
    size_t o = ((size_t)(b * 8 + chunk) * NM1 + half * 10 + mm) * MC + tid;
#pragma unroll
    for (int k = 0; k < 5; ++k) {
      ws[OFF_PRE + o + 256 * k] = ar[mm][k];
      ws[OFF_PIM + o + 256 * k] = ai[mm][k];
    }
  }
}

// ---- chunk-reduce + per-mode CxC complex matmul -------------------------
__global__ __launch_bounds__(256) void k_mode_mul(const float* __restrict__ kre,
                                                  const float* __restrict__ kim,
                                                  float* __restrict__ ws) {
  __shared__ float krT[64 * 65], kiT[64 * 65];   // [j][i], padded
  __shared__ float2 mm[16 * 64];                 // [b][j] (re,im)
  const int m1 = blockIdx.x / 20, m2 = blockIdx.x % 20;
  const int tid = threadIdx.x;
  const float* __restrict__ krb = kre + (size_t)(m1 * 20 + m2) * 64 * 64;
  const float* __restrict__ kib = kim + (size_t)(m1 * 20 + m2) * 64 * 64;
  for (int t = 0; t < 16; ++t) {
    int e = tid + 256 * t; int i = e >> 6, j = e & 63;
    krT[j * 65 + i] = krb[e];
    kiT[j * 65 + i] = kib[e];
  }
  for (int t = 0; t < 4; ++t) {
    int item = tid + 256 * t; int bb = item >> 6; int j = item & 63;
    float sr = 0.f, si = 0.f;
    for (int ch = 0; ch < 8; ++ch) {
      size_t o = ((size_t)(bb * 8 + ch) * NM1 + m1) * MC + m2 * 64 + j;
      sr += ws[OFF_PRE + o]; si += ws[OFF_PIM + o];
    }
    mm[bb * 64 + j] = make_float2(sr, si);
  }
  __syncthreads();
  const int i = tid & 63;
  for (int t = 0; t < 4; ++t) {
    int bb = (tid >> 6) + 4 * t;
    float arr = 0.f, aii = 0.f;
    for (int j = 0; j < 64; ++j) {
      float kr_ = krT[j * 65 + i], ki_ = kiT[j * 65 + i];
      float2 mv = mm[bb * 64 + j];
      arr += kr_ * mv.x - ki_ * mv.y;
      aii += kr_ * mv.y + ki_ * mv.x;
    }
    size_t o = ((size_t)(bb * NM1 + m1)) * MC + m2 * 64 + i;
    ws[OFF_MORE + o] = arr;
    ws[OFF_MOIM + o] = aii;
  }
}

// ---- inverse H-DFT: 4 h-rows per block share modesOut reads -------------
__global__ __launch_bounds__(256) void k_inv_h(float* __restrict__ ws) {
  const int b = blockIdx.x >> 6, h0 = blockIdx.x & 63;
  const int tid = threadIdx.x;
  const float2* __restrict__ e1 = (const float2*)(ws + OFF_E1);
  float gr[4][5], gi[4][5];
#pragma unroll
  for (int q = 0; q < 4; ++q)
#pragma unroll
    for (int k = 0; k < 5; ++k) { gr[q][k] = 0.f; gi[q][k] = 0.f; }
  for (int m1 = 0; m1 < 20; ++m1) {
    size_t mb = ((size_t)(b * NM1 + m1)) * MC + tid;
    float mr[5], mi[5];
#pragma unroll
    for (int k = 0; k < 5; ++k) {
      mr[k] = ws[OFF_MORE + mb + 256 * k];
      mi[k] = ws[OFF_MOIM + mb + 256 * k];
    }
#pragma unroll
    for (int q = 0; q < 4; ++q) {
      float2 cs = e1[m1 * 256 + h0 + 64 * q];    // multiply by (c + i s)
#pragma unroll
      for (int k = 0; k < 5; ++k) {
        gr[q][k] += mr[k] * cs.x - mi[k] * cs.y;
        gi[q][k] += mr[k] * cs.y + mi[k] * cs.x;
      }
    }
  }
#pragma unroll
  for (int q = 0; q < 4; ++q) {
    size_t gb = (size_t)(b * 256 + h0 + 64 * q) * MC + tid;
#pragma unroll
    for (int k = 0; k < 5; ++k) {
      ws[OFF_TWRE + gb + 256 * k] = gr[q][k];
      ws[OFF_TWIM + gb + 256 * k] = gi[q][k];
    }
  }
}

// ---- fused inverse-W synthesis + linear + residual ----------------------
__global__ __launch_bounds__(256) void k_final(const float* __restrict__ pts,
                                               const float* __restrict__ wlin,
                                               const float* __restrict__ ws,
                                               float* __restrict__ out) {
  constexpr int PS = 264;                        // pT row stride (ushorts), 528B = 33*16
  __shared__ unsigned short pT[64 * PS];         // [j][w] bf16   (33,792 B)
  __shared__ unsigned short wlt[64 * 64];        // [j][c] bf16   ( 8,192 B)
  __shared__ float glr[MC], gli[MC];             //               (10,240 B)
  const int tid = threadIdx.x;
  const int r = blockIdx.x;                      // b*256+h
  const float* __restrict__ prow = pts + (size_t)r * RC;

  for (int t = 0; t < 16; ++t) {                 // stage points, transposed, bf16
    int e4 = (tid + 256 * t) * 4;
    int w = e4 >> 6, j = e4 & 63;
    float4 v = *(const float4*)(prow + e4);
    pT[(j + 0) * PS + w] = f2bf(v.x);
    pT[(j + 1) * PS + w] = f2bf(v.y);
    pT[(j + 2) * PS + w] = f2bf(v.z);
    pT[(j + 3) * PS + w] = f2bf(v.w);
  }
  for (int t = 0; t < 16; ++t) {                 // stage w_lin transposed, bf16
    int e = tid + 256 * t;
    wlt[(e & 63) * 64 + (e >> 6)] = f2bf(wlin[e]);
  }
  size_t gb = (size_t)r * MC;                    // stage g row (fp32)
  for (int t = 0; t < 5; ++t) {
    glr[tid + 256 * t] = ws[OFF_TWRE + gb + tid + 256 * t];
    gli[tid + 256 * t] = ws[OFF_TWIM + gb + tid + 256 * t];
  }
  __syncthreads();

  const int tc = tid & 7, tw = tid >> 3;
  const int c0 = tc * 8, w0 = tw * 8;
  float acc[8][8];
#pragma unroll
  for (int a = 0; a < 8; ++a)
#pragma unroll
    for (int b2 = 0; b2 < 8; ++b2) acc[a][b2] = 0.f;

  // spectral synthesis
  const float* __restrict__ ikc = ws + OFF_IKC;
  const float* __restrict__ iks = ws + OFF_IKS;
  for (int ky = 0; ky < 20; ++ky) {
    float grv[8], giv[8], kcv[8], ksv[8];
    *(float4*)(grv)     = *(const float4*)(glr + ky * 64 + c0);
    *(float4*)(grv + 4) = *(const float4*)(glr + ky * 64 + c0 + 4);
    *(float4*)(giv)     = *(const float4*)(gli + ky * 64 + c0);
    *(float4*)(giv + 4) = *(const float4*)(gli + ky * 64 + c0 + 4);
    *(float4*)(kcv)     = *(const float4*)(ikc + ky * 256 + w0);
    *(float4*)(kcv + 4) = *(const float4*)(ikc + ky * 256 + w0 + 4);
    *(float4*)(ksv)     = *(const float4*)(iks + ky * 256 + w0);
    *(float4*)(ksv + 4) = *(const float4*)(iks + ky * 256 + w0 + 4);
#pragma unroll
    for (int ww = 0; ww < 8; ++ww)
#pragma unroll
      for (int cc = 0; cc < 8; ++cc)
        acc[ww][cc] += kcv[ww] * grv[cc] + ksv[ww] * giv[cc];
  }
  // linear: p @ w_lin^T
  for (int j = 0; j < 64; ++j) {
    uint4 pu = *(const uint4*)(pT + j * PS + w0);
    uint4 wu = *(const uint4*)(wlt + j * 64 + c0);
    float pw[8], wc[8];
    unpack8(pu, pw); unpack8(wu, wc);
#pragma unroll
    for (int ww = 0; ww < 8; ++ww)
#pragma unroll
      for (int cc = 0; cc < 8; ++cc)
        acc[ww][cc] += pw[ww] * wc[cc];
  }
  // residual
#pragma unroll
  for (int cc = 0; cc < 8; ++cc) {
    uint4 ru = *(const uint4*)(pT + (c0 + cc) * PS + w0);
    float rv[8];
    unpack8(ru, rv);
#pragma unroll
    for (int ww = 0; ww < 8; ++ww) acc[ww][cc] += rv[ww];
  }
  // store
  float* orow = out + (size_t)r * RC;
#pragma unroll
  for (int ww = 0; ww < 8; ++ww) {
    *(float4*)(orow + (w0 + ww) * 64 + c0) =
        make_float4(acc[ww][0], acc[ww][1], acc[ww][2], acc[ww][3]);
    *(float4*)(orow + (w0 + ww) * 64 + c0 + 4) =
        make_float4(acc[ww][4], acc[ww][5], acc[ww][6], acc[ww][7]);
  }
}

extern "C" void kernel_launch(void* const* d_in, const int* in_sizes, int n_in,
                              void* d_out, int out_size, void* d_ws, size_t ws_size,
                              hipStream_t stream) {
  const float* pts  = (const float*)d_in[0];
  const float* kre  = (const float*)d_in[1];
  const float* kim  = (const float*)d_in[2];
  const float* wlin = (const float*)d_in[3];
  float* out = (float*)d_out;
  float* ws  = (float*)d_ws;
  k_tables  <<<dim3(20),   dim3(256), 0, stream>>>(ws);
  k_fwd_w   <<<dim3(1024), dim3(256), 0, stream>>>(pts, ws);
  k_fwd_h   <<<dim3(256),  dim3(256), 0, stream>>>(ws);
  k_mode_mul<<<dim3(400),  dim3(256), 0, stream>>>(kre, kim, ws);
  k_inv_h   <<<dim3(1024), dim3(256), 0, stream>>>(ws);
  k_final   <<<dim3(4096), dim3(256), 0, stream>>>(pts, wlin, ws, out);
}